// Round 1
// baseline (153.733 us; speedup 1.0000x reference)
//
#include <hip/hip_runtime.h>
#include <math.h>

#define NUM_EXPERTS 64
#define TOP_K_      2
#define HIDDEN_     1024
#define B_          128
#define L_          512
#define C_          1024
#define ROWS_PER_BLOCK 4

// ---------------------------------------------------------------------------
// Kernel 1: gating. One block, 256 threads.
//   hidden = gelu_exact(W1[task] + b1)            (1024)
//   logits[e] = sum_h hidden[h] * W2[h*128 + e]   (e < 64)
//   probs = softmax(logits) + 1e-4
//   top-2 -> (i1,v1),(i2,v2) stored in ws; expert_mask written (128.0 / 0.0)
// ---------------------------------------------------------------------------
__global__ void gating_kernel(const float* __restrict__ W1,
                              const float* __restrict__ b1,
                              const float* __restrict__ W2,
                              const int*   __restrict__ task_index,
                              float* __restrict__ ws,
                              float* __restrict__ expert_mask) {
    __shared__ float hidden[HIDDEN_];
    __shared__ float praw[NUM_EXPERTS];

    const int tid  = threadIdx.x;
    const int task = task_index[0];

    for (int h = tid; h < HIDDEN_; h += 256) {
        float x = W1[task * HIDDEN_ + h] + b1[h];
        // exact GELU: x * 0.5 * (1 + erf(x / sqrt(2)))
        hidden[h] = 0.5f * x * (1.0f + erff(x * 0.7071067811865475f));
    }
    __syncthreads();

    if (tid < NUM_EXPERTS) {
        float acc = 0.0f;
        for (int h = 0; h < HIDDEN_; ++h) {
            acc += hidden[h] * W2[h * (2 * NUM_EXPERTS) + tid];  // broadcast LDS read
        }
        praw[tid] = acc;
    }
    __syncthreads();

    // threads 0..63 == wave 0 exactly (wavefront = 64)
    if (tid < NUM_EXPERTS) {
        float v = praw[tid];

        // wave-wide max
        float m = v;
        #pragma unroll
        for (int off = 32; off > 0; off >>= 1) m = fmaxf(m, __shfl_xor(m, off));
        float e = expf(v - m);
        float s = e;
        #pragma unroll
        for (int off = 32; off > 0; off >>= 1) s += __shfl_xor(s, off);
        float p = e / s + 1.0e-4f;

        // top-1 argmax (tie -> smaller index, matching top_k)
        float v1 = p; int i1 = tid;
        #pragma unroll
        for (int off = 32; off > 0; off >>= 1) {
            float ov = __shfl_xor(v1, off);
            int   oi = __shfl_xor(i1, off);
            if (ov > v1 || (ov == v1 && oi < i1)) { v1 = ov; i1 = oi; }
        }
        // top-2: exclude i1
        float v2 = (tid == i1) ? -1.0f : p; int i2 = tid;
        #pragma unroll
        for (int off = 32; off > 0; off >>= 1) {
            float ov = __shfl_xor(v2, off);
            int   oi = __shfl_xor(i2, off);
            if (ov > v2 || (ov == v2 && oi < i2)) { v2 = ov; i2 = oi; }
        }

        if (tid == 0) {
            ws[0] = v1;
            ws[1] = v2;
            ((int*)ws)[2] = i1;
            ((int*)ws)[3] = i2;
        }
        // expert_size == B_ for both selected experts (gates always > 0)
        expert_mask[tid] = (tid == i1 || tid == i2) ? (float)B_ : 0.0f;
    }
}

// ---------------------------------------------------------------------------
// Kernel 2: token_mask[l] = sum_b ( P[b,e0,l] + P[b,e1,l] )
// ---------------------------------------------------------------------------
__global__ void token_mask_kernel(const float* __restrict__ P,
                                  const float* __restrict__ ws,
                                  float* __restrict__ token_mask) {
    const int l = blockIdx.x * blockDim.x + threadIdx.x;
    if (l >= L_) return;
    const int e0 = ((const int*)ws)[2];
    const int e1 = ((const int*)ws)[3];
    float acc = 0.0f;
    for (int b = 0; b < B_; ++b) {
        acc += P[((size_t)b * NUM_EXPERTS + e0) * L_ + l];
        acc += P[((size_t)b * NUM_EXPERTS + e1) * L_ + l];
    }
    token_mask[l] = acc;
}

// ---------------------------------------------------------------------------
// Kernel 3 (heavy, memory-bound):
//   y[b,l,c] = x[b,l,c] * ( g0*P[b,e0,l] + g1*P[b,e1,l] )
// One 256-thread block handles ROWS_PER_BLOCK rows of C_=1024 floats
// (one float4 per thread per row).
// ---------------------------------------------------------------------------
__global__ void moe_y_kernel(const float* __restrict__ x,
                             const float* __restrict__ P,
                             const float* __restrict__ ws,
                             float* __restrict__ y) {
    const float g0 = ws[0];
    const float g1 = ws[1];
    const int   e0 = ((const int*)ws)[2];
    const int   e1 = ((const int*)ws)[3];

    const int row0 = blockIdx.x * ROWS_PER_BLOCK;

    #pragma unroll
    for (int r = 0; r < ROWS_PER_BLOCK; ++r) {
        const int row = row0 + r;          // row = b*L_ + l
        const int b   = row >> 9;          // / L_
        const int l   = row & (L_ - 1);    // % L_

        // same address across all lanes -> broadcast load (cached)
        const float p0 = P[((size_t)b * NUM_EXPERTS + e0) * L_ + l];
        const float p1 = P[((size_t)b * NUM_EXPERTS + e1) * L_ + l];
        const float s  = fmaf(g0, p0, g1 * p1);

        const float4* x4 = (const float4*)(x + (size_t)row * C_);
        float4*       y4 = (float4*)(y + (size_t)row * C_);
        float4 v = x4[threadIdx.x];
        v.x *= s; v.y *= s; v.z *= s; v.w *= s;
        y4[threadIdx.x] = v;
    }
}

extern "C" void kernel_launch(void* const* d_in, const int* in_sizes, int n_in,
                              void* d_out, int out_size, void* d_ws, size_t ws_size,
                              hipStream_t stream) {
    const float* x    = (const float*)d_in[0];   // (128, 512, 1024)
    const float* P    = (const float*)d_in[1];   // (128, 64, 512)
    const float* W1   = (const float*)d_in[2];   // (8, 1024)
    const float* b1   = (const float*)d_in[3];   // (1024,)
    const float* W2   = (const float*)d_in[4];   // (1024, 128)
    const int*   task = (const int*)d_in[5];     // scalar

    float* out         = (float*)d_out;
    float* y           = out;                                  // 128*512*1024
    float* expert_mask = out + (size_t)B_ * L_ * C_;           // 64
    float* token_mask  = expert_mask + NUM_EXPERTS;            // 512
    float* ws          = (float*)d_ws;

    gating_kernel<<<1, 256, 0, stream>>>(W1, b1, W2, task, ws, expert_mask);
    token_mask_kernel<<<(L_ + 255) / 256, 256, 0, stream>>>(P, ws, token_mask);

    const int n_rows = B_ * L_;
    moe_y_kernel<<<n_rows / ROWS_PER_BLOCK, 256, 0, stream>>>(x, P, ws, y);
}